// Round 2
// baseline (133.749 us; speedup 1.0000x reference)
//
#include <hip/hip_runtime.h>
#include <math.h>
#include <stdint.h>

#define B_ 16
#define L_ 50
#define LU_ 60
#define KU_ 100
#define DIM_ 60
#define V_ 2000
#define MAXVL_ 10
#define MIN_WL_ 4
#define MAX_WL_ 10
#define NE_ 7            // MAX_WL - MIN_WL + 1
#define NEG_ (-9999.9f)
#define IDC_ 3.5f
#define LOG_UNEXT_ (-4.6051701859880913680359829093687f)  // log(0.01)
#define CTXW_ 0.1f

// workspace layout (float element offsets)
#define WS_KU   0                 // ku_char_repr: 60*60 = 3600
#define WS_CLP  3600              // char_log_probs: 60*100 = 6000
#define WS_PLP  9600              // pos_lp: B*L*KU = 80000
#define WS_BEST_BYTES (89600u * 4u)  // 16 x u64 best keys

// -------------------------------------------------------------------------
// Kernel 1: ku_char_repr = aligner_weight @ unit_repr;
//           char_log_probs = log_softmax(ku_char_repr @ unit_repr^T);
//           alignment = exp(char_log_probs) -> d_out[64..6064)
//           also zero the per-batch atomic best slots.
__global__ __launch_bounds__(256) void prep_kernel(
    const float* __restrict__ unit_repr,      // (KU, DIM)
    const float* __restrict__ aligner_weight, // (LU, KU)
    float* __restrict__ ws_f,
    unsigned long long* __restrict__ g_best,
    float* __restrict__ out_align)            // (LU, KU)
{
  __shared__ float s_ur[KU_ * DIM_];
  __shared__ float s_ku[LU_ * DIM_];
  __shared__ float s_lg[LU_ * KU_];
  __shared__ float s_ls[LU_];
  int t = threadIdx.x;
  if (t < B_) g_best[t] = 0ull;
  for (int i = t; i < KU_ * DIM_; i += 256) s_ur[i] = unit_repr[i];
  __syncthreads();
  for (int i = t; i < LU_ * DIM_; i += 256) {
    int r = i / DIM_, c = i % DIM_;
    float acc = 0.f;
    for (int k = 0; k < KU_; ++k) acc += aligner_weight[r * KU_ + k] * s_ur[k * DIM_ + c];
    s_ku[i] = acc;
    ws_f[WS_KU + i] = acc;
  }
  __syncthreads();
  for (int i = t; i < LU_ * KU_; i += 256) {
    int r = i / KU_, k = i % KU_;
    float acc = 0.f;
    for (int d = 0; d < DIM_; ++d) acc += s_ku[r * DIM_ + d] * s_ur[k * DIM_ + d];
    s_lg[i] = acc;
  }
  __syncthreads();
  if (t < LU_) {
    float m = -1e30f;
    for (int k = 0; k < KU_; ++k) m = fmaxf(m, s_lg[t * KU_ + k]);
    float s = 0.f;
    for (int k = 0; k < KU_; ++k) s += expf(s_lg[t * KU_ + k] - m);
    s_ls[t] = m + logf(s);
  }
  __syncthreads();
  for (int i = t; i < LU_ * KU_; i += 256) {
    float lp = s_lg[i] - s_ls[i / KU_];
    ws_f[WS_CLP + i] = lp;
    out_align[i] = expf(lp);
  }
}

// -------------------------------------------------------------------------
// Kernel 2: per (b,l): emb gather -> width-3 conv -> ctx logits ->
//           log_softmax -> pos_lp = clp[uid] + 0.1*ctx_lp
__global__ __launch_bounds__(128) void ctx_kernel(
    const int* __restrict__ uid,        // (B, L)
    const float* __restrict__ unit_repr,// (KU, DIM)
    const float* __restrict__ conv_w,   // (DIM, DIM, 3)
    const float* __restrict__ conv_b,   // (DIM,)
    const float* __restrict__ ws_f,     // ku_char_repr + char_log_probs
    float* __restrict__ ws_plp)         // (B*L, KU)
{
  int bl = blockIdx.x;
  int b = bl / L_, l = bl % L_;
  int t = threadIdx.x;
  __shared__ float sx[3 * DIM_];
  __shared__ float swr[DIM_];
  __shared__ float slog[KU_];
  __shared__ float sred[128];

  // NOTE: 3*DIM_=180 > blockDim=128 — MUST be a strided loop (round-1 bug:
  // guarded single write left sx[128..179] uninitialized).
  for (int i = t; i < 3 * DIM_; i += 128) {
    int d = i / DIM_, c = i % DIM_;
    int ld = l + d - 1;
    float vv = 0.f;
    if (ld >= 0 && ld < L_) {
      int u = uid[b * L_ + ld];
      vv = ws_f[WS_KU + u * DIM_ + c];
    }
    sx[i] = vv;
  }
  __syncthreads();
  if (t < DIM_) {
    float acc = conv_b[t];
    for (int i = 0; i < DIM_; ++i) {
      acc += sx[0 * DIM_ + i] * conv_w[t * DIM_ * 3 + i * 3 + 0];
      acc += sx[1 * DIM_ + i] * conv_w[t * DIM_ * 3 + i * 3 + 1];
      acc += sx[2 * DIM_ + i] * conv_w[t * DIM_ * 3 + i * 3 + 2];
    }
    swr[t] = acc;
  }
  __syncthreads();
  if (t < KU_) {
    float acc = 0.f;
    for (int d = 0; d < DIM_; ++d) acc += swr[d] * unit_repr[t * DIM_ + d];
    slog[t] = acc;
  }
  __syncthreads();
  sred[t] = (t < KU_) ? slog[t] : -1e30f;
  __syncthreads();
  for (int off = 64; off > 0; off >>= 1) {
    if (t < off) sred[t] = fmaxf(sred[t], sred[t + off]);
    __syncthreads();
  }
  float m = sred[0];
  __syncthreads();
  sred[t] = (t < KU_) ? expf(slog[t] - m) : 0.f;
  __syncthreads();
  for (int off = 64; off > 0; off >>= 1) {
    if (t < off) sred[t] += sred[t + off];
    __syncthreads();
  }
  float ls = m + logf(sred[0]);
  if (t < KU_) {
    int u = uid[b * L_ + l];
    float lp = slog[t] - ls;
    ws_plp[bl * KU_ + t] = ws_f[WS_CLP + u * KU_ + t] + CTXW_ * lp;
  }
}

// -------------------------------------------------------------------------
// Kernel 3: the DP. grid (B*L, ceil(V/256)), 256 threads, one vocab per thread.
__global__ __launch_bounds__(256) void dp_kernel(
    const int* __restrict__ lengths,
    const int* __restrict__ vocab_ids,      // (V, MAXVL)
    const int* __restrict__ vocab_lengths,  // (V,)
    const float* __restrict__ ws_plp,       // (B*L, KU)
    unsigned long long* __restrict__ g_best)
{
  int bl = blockIdx.x;
  int b = bl / L_, l = bl % L_;
  int len_b = lengths[b];
  int imax = len_b - l;
  if (imax > MAX_WL_) imax = MAX_WL_;
  if (imax < MIN_WL_) return;  // uniform across block; no viable word here

  __shared__ float srows[MAX_WL_ * KU_];
  __shared__ unsigned long long swave[4];
  int t = threadIdx.x;
  int total = imax * KU_;
  for (int i = t; i < total; i += 256)
    srows[i] = ws_plp[(bl + (i / KU_)) * KU_ + (i % KU_)];
  __syncthreads();

  int v = blockIdx.y * 256 + t;
  unsigned long long bestKey = 0ull;
  if (v < V_) {
    int vid[MAXVL_];
#pragma unroll
    for (int j = 0; j < MAXVL_; ++j) vid[j] = vocab_ids[v * MAXVL_ + j];
    int vlen = vocab_lengths[v];
    float prev[MAXVL_ + 1];
#pragma unroll
    for (int j = 0; j <= MAXVL_; ++j) prev[j] = -IDC_ * (float)j;

    for (int i = 1; i <= imax; ++i) {
      const float* row = &srows[(i - 1) * KU_];
      float s[MAXVL_];
#pragma unroll
      for (int j = 0; j < MAXVL_; ++j) s[j] = row[vid[j]];
      float diag_in = prev[0];
      float rowprev = -IDC_ * (float)i;
      prev[0] = rowprev;
#pragma unroll
      for (int j = 1; j <= MAXVL_; ++j) {
        float tt = fmaxf(diag_in + s[j - 1], fmaxf(prev[j], rowprev) - IDC_);
        diag_in = prev[j];
        prev[j] = tt;
        rowprev = tt;
      }
      if (i >= MIN_WL_) {
        float ll = prev[MIN_WL_];
#pragma unroll
        for (int jj = MIN_WL_ + 1; jj <= MAXVL_; ++jj)
          if (vlen == jj) ll = prev[jj];
        float score = ll + (float)(len_b - i) * LOG_UNEXT_;
        unsigned int idx = (unsigned int)(l * (NE_ * V_) + (i - MIN_WL_) * V_ + v);
        unsigned int u = __float_as_uint(score);
        u = (u & 0x80000000u) ? ~u : (u | 0x80000000u);
        unsigned long long key =
            ((unsigned long long)u << 32) | (unsigned long long)(~idx);
        if (key > bestKey) bestKey = key;
      }
    }
  }

  // wave reduce (64 lanes)
#pragma unroll
  for (int off = 32; off > 0; off >>= 1) {
    unsigned long long o = __shfl_down(bestKey, off);
    if (o > bestKey) bestKey = o;
  }
  int wid = t >> 6;
  if ((t & 63) == 0) swave[wid] = bestKey;
  __syncthreads();
  if (t == 0) {
    unsigned long long k0 = swave[0];
    for (int w = 1; w < 4; ++w)
      if (swave[w] > k0) k0 = swave[w];
    atomicMax(g_best + b, k0);
  }
}

// -------------------------------------------------------------------------
// Kernel 4: decode per-batch best keys into (start, end, ll, vocab) floats.
__global__ void decode_kernel(const unsigned long long* __restrict__ g_best,
                              float* __restrict__ out)
{
  int t = threadIdx.x;
  if (t < B_) {
    unsigned long long key = g_best[t];
    unsigned int u = (unsigned int)(key >> 32);
    unsigned int idx = ~((unsigned int)(key & 0xFFFFFFFFull));
    unsigned int bits = (u & 0x80000000u) ? (u & 0x7FFFFFFFu) : ~u;
    float val = __uint_as_float(bits);
    int start = (int)(idx / (NE_ * V_));
    int rem = (int)(idx % (NE_ * V_));
    int e = rem / V_;
    int vv = rem % V_;
    out[t] = (float)start;
    out[B_ + t] = (float)(start + MIN_WL_ + e - 1);
    out[2 * B_ + t] = val;
    out[3 * B_ + t] = (float)vv;
  }
}

// -------------------------------------------------------------------------
extern "C" void kernel_launch(void* const* d_in, const int* in_sizes, int n_in,
                              void* d_out, int out_size, void* d_ws, size_t ws_size,
                              hipStream_t stream)
{
  const int* uid            = (const int*)d_in[0];
  const int* lengths        = (const int*)d_in[1];
  const float* unit_repr    = (const float*)d_in[2];
  const float* aligner_w    = (const float*)d_in[3];
  const float* conv_w       = (const float*)d_in[4];
  const float* conv_b       = (const float*)d_in[5];
  const int* vocab_ids      = (const int*)d_in[6];
  const int* vocab_lengths  = (const int*)d_in[7];
  float* out = (float*)d_out;
  float* ws_f = (float*)d_ws;
  unsigned long long* g_best =
      (unsigned long long*)((char*)d_ws + WS_BEST_BYTES);

  prep_kernel<<<1, 256, 0, stream>>>(unit_repr, aligner_w, ws_f, g_best,
                                     out + 4 * B_);
  ctx_kernel<<<B_ * L_, 128, 0, stream>>>(uid, unit_repr, conv_w, conv_b, ws_f,
                                          ws_f + WS_PLP);
  dim3 g3(B_ * L_, (V_ + 255) / 256);
  dp_kernel<<<g3, 256, 0, stream>>>(lengths, vocab_ids, vocab_lengths,
                                    ws_f + WS_PLP, g_best);
  decode_kernel<<<1, 64, 0, stream>>>(g_best, out);
}

// Round 3
// 125.404 us; speedup vs baseline: 1.0666x; 1.0666x over previous
//
#include <hip/hip_runtime.h>
#include <math.h>
#include <stdint.h>

#define B_ 16
#define L_ 50
#define LU_ 60
#define KU_ 100
#define DIM_ 60
#define V_ 2000
#define MAXVL_ 10
#define MIN_WL_ 4
#define MAX_WL_ 10
#define NE_ 7            // MAX_WL - MIN_WL + 1
#define IDC_ 3.5f
#define LOG_UNEXT_ (-4.6051701859880913680359829093687f)  // log(0.01)
#define CTXW_ 0.1f

// workspace layout (float element offsets)
#define WS_KU   0                 // ku_char_repr: 60*60 = 3600
#define WS_CLP  3600              // char_log_probs: 60*100 = 6000
#define WS_PLP  9600              // pos_lp: B*L*KU = 80000
#define WS_BEST_BYTES (89600u * 4u)  // 16 x u64 best keys

#define URP_ 61   // padded LDS stride for unit_repr rows (61 odd -> conflict-free)
#define CWP_ 61   // padded LDS stride for transposed conv_w

// -------------------------------------------------------------------------
// Kernel 1 (60 blocks, one per LU row):
//   ku_char_repr[r] = aligner_weight[r] @ unit_repr
//   char_log_probs[r] = log_softmax(ku_char_repr[r] @ unit_repr^T)
//   alignment[r] = exp(char_log_probs[r]) -> d_out[64..)
//   block 0 also zeros the per-batch atomic best slots.
__global__ __launch_bounds__(128) void prep_kernel(
    const float* __restrict__ unit_repr,      // (KU, DIM)
    const float* __restrict__ aligner_weight, // (LU, KU)
    float* __restrict__ ws_f,
    unsigned long long* __restrict__ g_best,
    float* __restrict__ out_align)            // (LU, KU)
{
  __shared__ float s_ur[KU_ * URP_];  // padded: row k at k*61
  __shared__ float s_aw[KU_];
  __shared__ float s_ku[DIM_];
  __shared__ float s_lg[KU_];
  __shared__ float sred[128];
  int r = blockIdx.x;   // 0..59
  int t = threadIdx.x;
  if (r == 0 && t < B_) g_best[t] = 0ull;
  for (int i = t; i < KU_ * DIM_; i += 128)
    s_ur[(i / DIM_) * URP_ + (i % DIM_)] = unit_repr[i];
  if (t < KU_) s_aw[t] = aligner_weight[r * KU_ + t];
  __syncthreads();
  if (t < DIM_) {
    float acc = 0.f;
    for (int k = 0; k < KU_; ++k) acc += s_aw[k] * s_ur[k * URP_ + t];
    s_ku[t] = acc;
    ws_f[WS_KU + r * DIM_ + t] = acc;
  }
  __syncthreads();
  if (t < KU_) {
    float acc = 0.f;
    for (int d = 0; d < DIM_; ++d) acc += s_ku[d] * s_ur[t * URP_ + d];
    s_lg[t] = acc;
  }
  __syncthreads();
  sred[t] = (t < KU_) ? s_lg[t] : -1e30f;
  __syncthreads();
  for (int off = 64; off > 0; off >>= 1) {
    if (t < off) sred[t] = fmaxf(sred[t], sred[t + off]);
    __syncthreads();
  }
  float m = sred[0];
  __syncthreads();
  sred[t] = (t < KU_) ? expf(s_lg[t] - m) : 0.f;
  __syncthreads();
  for (int off = 64; off > 0; off >>= 1) {
    if (t < off) sred[t] += sred[t + off];
    __syncthreads();
  }
  float ls = m + logf(sred[0]);
  if (t < KU_) {
    float lp = s_lg[t] - ls;
    ws_f[WS_CLP + r * KU_ + t] = lp;
    out_align[r * KU_ + t] = expf(lp);
  }
}

// -------------------------------------------------------------------------
// Kernel 2: per (b,l): emb gather -> width-3 conv -> ctx logits ->
//           log_softmax -> pos_lp = clp[uid] + 0.1*ctx_lp
// unit_repr and conv_w staged in LDS with conflict-free layouts.
__global__ __launch_bounds__(128) void ctx_kernel(
    const int* __restrict__ uid,        // (B, L)
    const float* __restrict__ unit_repr,// (KU, DIM)
    const float* __restrict__ conv_w,   // (DIM, DIM, 3)
    const float* __restrict__ conv_b,   // (DIM,)
    const float* __restrict__ ws_f,     // ku_char_repr + char_log_probs
    float* __restrict__ ws_plp)         // (B*L, KU)
{
  int bl = blockIdx.x;
  int b = bl / L_, l = bl % L_;
  int t = threadIdx.x;
  __shared__ float s_ur[KU_ * URP_];          // row t at t*61, 6100 f
  __shared__ float s_cw[3 * DIM_ * CWP_];     // [(i*3+d)*61 + o], 10980 f
  __shared__ float sx[3 * DIM_];
  __shared__ float swr[DIM_];
  __shared__ float slog[KU_];
  __shared__ float sred[128];

  for (int i = t; i < KU_ * DIM_; i += 128)
    s_ur[(i / DIM_) * URP_ + (i % DIM_)] = unit_repr[i];
  for (int i = t; i < DIM_ * DIM_ * 3; i += 128) {
    int o = i / (3 * DIM_), id = i % (3 * DIM_);
    s_cw[id * CWP_ + o] = conv_w[i];
  }
  // strided: 3*DIM_=180 > 128 threads
  for (int i = t; i < 3 * DIM_; i += 128) {
    int d = i / DIM_, c = i % DIM_;
    int ld = l + d - 1;
    float vv = 0.f;
    if (ld >= 0 && ld < L_) {
      int u = uid[b * L_ + ld];
      vv = ws_f[WS_KU + u * DIM_ + c];
    }
    sx[i] = vv;
  }
  __syncthreads();
  if (t < DIM_) {
    float acc = conv_b[t];
    for (int i = 0; i < DIM_; ++i) {
      acc += sx[0 * DIM_ + i] * s_cw[(i * 3 + 0) * CWP_ + t];
      acc += sx[1 * DIM_ + i] * s_cw[(i * 3 + 1) * CWP_ + t];
      acc += sx[2 * DIM_ + i] * s_cw[(i * 3 + 2) * CWP_ + t];
    }
    swr[t] = acc;
  }
  __syncthreads();
  if (t < KU_) {
    float acc = 0.f;
    for (int d = 0; d < DIM_; ++d) acc += swr[d] * s_ur[t * URP_ + d];
    slog[t] = acc;
  }
  __syncthreads();
  sred[t] = (t < KU_) ? slog[t] : -1e30f;
  __syncthreads();
  for (int off = 64; off > 0; off >>= 1) {
    if (t < off) sred[t] = fmaxf(sred[t], sred[t + off]);
    __syncthreads();
  }
  float m = sred[0];
  __syncthreads();
  sred[t] = (t < KU_) ? expf(slog[t] - m) : 0.f;
  __syncthreads();
  for (int off = 64; off > 0; off >>= 1) {
    if (t < off) sred[t] += sred[t + off];
    __syncthreads();
  }
  float ls = m + logf(sred[0]);
  if (t < KU_) {
    int u = uid[b * L_ + l];
    float lp = slog[t] - ls;
    ws_plp[bl * KU_ + t] = ws_f[WS_CLP + u * KU_ + t] + CTXW_ * lp;
  }
}

// -------------------------------------------------------------------------
// Kernel 3: the DP. grid (B*L, ceil(V/256)), 256 threads, one vocab per thread.
__global__ __launch_bounds__(256) void dp_kernel(
    const int* __restrict__ lengths,
    const int* __restrict__ vocab_ids,      // (V, MAXVL)
    const int* __restrict__ vocab_lengths,  // (V,)
    const float* __restrict__ ws_plp,       // (B*L, KU)
    unsigned long long* __restrict__ g_best)
{
  int bl = blockIdx.x;
  int b = bl / L_, l = bl % L_;
  int len_b = lengths[b];
  int imax = len_b - l;
  if (imax > MAX_WL_) imax = MAX_WL_;
  if (imax < MIN_WL_) return;  // uniform across block; no viable word here

  __shared__ float srows[MAX_WL_ * KU_];
  __shared__ unsigned long long swave[4];
  int t = threadIdx.x;
  int total = imax * KU_;
  for (int i = t; i < total; i += 256)
    srows[i] = ws_plp[(bl + (i / KU_)) * KU_ + (i % KU_)];
  __syncthreads();

  int v = blockIdx.y * 256 + t;
  unsigned long long bestKey = 0ull;
  if (v < V_) {
    int vid[MAXVL_];
#pragma unroll
    for (int j = 0; j < MAXVL_; ++j) vid[j] = vocab_ids[v * MAXVL_ + j];
    int vlen = vocab_lengths[v];
    float prev[MAXVL_ + 1];
#pragma unroll
    for (int j = 0; j <= MAXVL_; ++j) prev[j] = -IDC_ * (float)j;

    for (int i = 1; i <= imax; ++i) {
      const float* row = &srows[(i - 1) * KU_];
      float s[MAXVL_];
#pragma unroll
      for (int j = 0; j < MAXVL_; ++j) s[j] = row[vid[j]];
      float diag_in = prev[0];
      float rowprev = -IDC_ * (float)i;
      prev[0] = rowprev;
#pragma unroll
      for (int j = 1; j <= MAXVL_; ++j) {
        float tt = fmaxf(diag_in + s[j - 1], fmaxf(prev[j], rowprev) - IDC_);
        diag_in = prev[j];
        prev[j] = tt;
        rowprev = tt;
      }
      if (i >= MIN_WL_) {
        float ll = prev[MIN_WL_];
#pragma unroll
        for (int jj = MIN_WL_ + 1; jj <= MAXVL_; ++jj)
          if (vlen == jj) ll = prev[jj];
        float score = ll + (float)(len_b - i) * LOG_UNEXT_;
        unsigned int idx = (unsigned int)(l * (NE_ * V_) + (i - MIN_WL_) * V_ + v);
        unsigned int u = __float_as_uint(score);
        u = (u & 0x80000000u) ? ~u : (u | 0x80000000u);
        unsigned long long key =
            ((unsigned long long)u << 32) | (unsigned long long)(~idx);
        if (key > bestKey) bestKey = key;
      }
    }
  }

  // wave reduce (64 lanes)
#pragma unroll
  for (int off = 32; off > 0; off >>= 1) {
    unsigned long long o = __shfl_down(bestKey, off);
    if (o > bestKey) bestKey = o;
  }
  int wid = t >> 6;
  if ((t & 63) == 0) swave[wid] = bestKey;
  __syncthreads();
  if (t == 0) {
    unsigned long long k0 = swave[0];
    for (int w = 1; w < 4; ++w)
      if (swave[w] > k0) k0 = swave[w];
    atomicMax(g_best + b, k0);
  }
}

// -------------------------------------------------------------------------
// Kernel 4: decode per-batch best keys into (start, end, ll, vocab) floats.
__global__ void decode_kernel(const unsigned long long* __restrict__ g_best,
                              float* __restrict__ out)
{
  int t = threadIdx.x;
  if (t < B_) {
    unsigned long long key = g_best[t];
    unsigned int u = (unsigned int)(key >> 32);
    unsigned int idx = ~((unsigned int)(key & 0xFFFFFFFFull));
    unsigned int bits = (u & 0x80000000u) ? (u & 0x7FFFFFFFu) : ~u;
    float val = __uint_as_float(bits);
    int start = (int)(idx / (NE_ * V_));
    int rem = (int)(idx % (NE_ * V_));
    int e = rem / V_;
    int vv = rem % V_;
    out[t] = (float)start;
    out[B_ + t] = (float)(start + MIN_WL_ + e - 1);
    out[2 * B_ + t] = val;
    out[3 * B_ + t] = (float)vv;
  }
}

// -------------------------------------------------------------------------
extern "C" void kernel_launch(void* const* d_in, const int* in_sizes, int n_in,
                              void* d_out, int out_size, void* d_ws, size_t ws_size,
                              hipStream_t stream)
{
  const int* uid            = (const int*)d_in[0];
  const int* lengths        = (const int*)d_in[1];
  const float* unit_repr    = (const float*)d_in[2];
  const float* aligner_w    = (const float*)d_in[3];
  const float* conv_w       = (const float*)d_in[4];
  const float* conv_b       = (const float*)d_in[5];
  const int* vocab_ids      = (const int*)d_in[6];
  const int* vocab_lengths  = (const int*)d_in[7];
  float* out = (float*)d_out;
  float* ws_f = (float*)d_ws;
  unsigned long long* g_best =
      (unsigned long long*)((char*)d_ws + WS_BEST_BYTES);

  prep_kernel<<<LU_, 128, 0, stream>>>(unit_repr, aligner_w, ws_f, g_best,
                                       out + 4 * B_);
  ctx_kernel<<<B_ * L_, 128, 0, stream>>>(uid, unit_repr, conv_w, conv_b, ws_f,
                                          ws_f + WS_PLP);
  dim3 g3(B_ * L_, (V_ + 255) / 256);
  dp_kernel<<<g3, 256, 0, stream>>>(lengths, vocab_ids, vocab_lengths,
                                    ws_f + WS_PLP, g_best);
  decode_kernel<<<1, 64, 0, stream>>>(g_best, out);
}

// Round 4
// 113.150 us; speedup vs baseline: 1.1820x; 1.1083x over previous
//
#include <hip/hip_runtime.h>
#include <math.h>
#include <stdint.h>

#define B_ 16
#define L_ 50
#define LU_ 60
#define KU_ 100
#define DIM_ 60
#define V_ 2000
#define MAXVL_ 10
#define MIN_WL_ 4
#define MAX_WL_ 10
#define NE_ 7            // MAX_WL - MIN_WL + 1
#define IDC_ 3.5f
#define LOG_UNEXT_ (-4.6051701859880913680359829093687f)  // log(0.01)
#define CTXW_ 0.1f

// workspace layout (float element offsets)
#define WS_KU   0                 // ku_char_repr: 60*60 = 3600
#define WS_CLP  3600              // char_log_probs: 60*100 = 6000
#define WS_PLP  9600              // pos_lp: B*L*KU = 80000  (16B-aligned: 9600*4=38400)
#define WS_BEST_BYTES (89600u * 4u)  // 16 x (8-u64-padded) best keys
#define BEST_STRIDE 8             // 64 B between per-batch atomic slots

#define URP_ 61   // padded LDS stride (odd -> conflict-free strided reads)
#define CWP_ 61

// -------------------------------------------------------------------------
// Kernel 1 (60 blocks, one per LU row).
__global__ __launch_bounds__(128) void prep_kernel(
    const float* __restrict__ unit_repr,      // (KU, DIM)
    const float* __restrict__ aligner_weight, // (LU, KU)
    float* __restrict__ ws_f,
    unsigned long long* __restrict__ g_best,
    float* __restrict__ out_align)            // (LU, KU)
{
  __shared__ float s_ur[KU_ * URP_];
  __shared__ float s_aw[KU_];
  __shared__ float s_ku[DIM_];
  __shared__ float s_lg[KU_];
  __shared__ float sred[128];
  int r = blockIdx.x;
  int t = threadIdx.x;
  if (r == 0 && t < B_) g_best[t * BEST_STRIDE] = 0ull;
  for (int i = t; i < KU_ * DIM_; i += 128)
    s_ur[(i / DIM_) * URP_ + (i % DIM_)] = unit_repr[i];
  if (t < KU_) s_aw[t] = aligner_weight[r * KU_ + t];
  __syncthreads();
  if (t < DIM_) {
    float acc = 0.f;
    for (int k = 0; k < KU_; ++k) acc += s_aw[k] * s_ur[k * URP_ + t];
    s_ku[t] = acc;
    ws_f[WS_KU + r * DIM_ + t] = acc;
  }
  __syncthreads();
  if (t < KU_) {
    float acc = 0.f;
    for (int d = 0; d < DIM_; ++d) acc += s_ku[d] * s_ur[t * URP_ + d];
    s_lg[t] = acc;
  }
  __syncthreads();
  sred[t] = (t < KU_) ? s_lg[t] : -1e30f;
  __syncthreads();
  for (int off = 64; off > 0; off >>= 1) {
    if (t < off) sred[t] = fmaxf(sred[t], sred[t + off]);
    __syncthreads();
  }
  float m = sred[0];
  __syncthreads();
  sred[t] = (t < KU_) ? expf(s_lg[t] - m) : 0.f;
  __syncthreads();
  for (int off = 64; off > 0; off >>= 1) {
    if (t < off) sred[t] += sred[t + off];
    __syncthreads();
  }
  float ls = m + logf(sred[0]);
  if (t < KU_) {
    float lp = s_lg[t] - ls;
    ws_f[WS_CLP + r * KU_ + t] = lp;
    out_align[r * KU_ + t] = expf(lp);
  }
}

// -------------------------------------------------------------------------
// Kernel 2: per (b,l), 256 threads. float4 staging of weights into LDS.
__global__ __launch_bounds__(256) void ctx_kernel(
    const int* __restrict__ uid,        // (B, L)
    const float* __restrict__ unit_repr,// (KU, DIM)
    const float* __restrict__ conv_w,   // (DIM, DIM, 3)
    const float* __restrict__ conv_b,   // (DIM,)
    const float* __restrict__ ws_f,
    float* __restrict__ ws_plp)         // (B*L, KU)
{
  int bl = blockIdx.x;
  int b = bl / L_, l = bl % L_;
  int t = threadIdx.x;
  __shared__ float s_ur[KU_ * URP_];          // 6100 f
  __shared__ float s_cw[3 * DIM_ * CWP_];     // transposed: [(i*3+d)*61 + o]
  __shared__ float sx[3 * DIM_];
  __shared__ float swr[DIM_];
  __shared__ float slog[KU_];
  __shared__ float sred[256];

  // float4 staging: unit_repr 6000 dwords = 1500 f4; conv_w 10800 = 2700 f4
  const float4* ur4 = (const float4*)unit_repr;
  for (int k = t; k < (KU_ * DIM_) / 4; k += 256) {
    float4 v = ur4[k];
    int i0 = 4 * k;
    s_ur[((i0 + 0) / DIM_) * URP_ + ((i0 + 0) % DIM_)] = v.x;
    s_ur[((i0 + 1) / DIM_) * URP_ + ((i0 + 1) % DIM_)] = v.y;
    s_ur[((i0 + 2) / DIM_) * URP_ + ((i0 + 2) % DIM_)] = v.z;
    s_ur[((i0 + 3) / DIM_) * URP_ + ((i0 + 3) % DIM_)] = v.w;
  }
  const float4* cw4 = (const float4*)conv_w;
  for (int k = t; k < (DIM_ * DIM_ * 3) / 4; k += 256) {
    float4 v = cw4[k];
    int i0 = 4 * k;
    float vv[4] = {v.x, v.y, v.z, v.w};
#pragma unroll
    for (int e = 0; e < 4; ++e) {
      int idx = i0 + e;
      int o = idx / (3 * DIM_), id = idx % (3 * DIM_);
      s_cw[id * CWP_ + o] = vv[e];
    }
  }
  if (t < 3 * DIM_) {
    int d = t / DIM_, c = t % DIM_;
    int ld = l + d - 1;
    float vv = 0.f;
    if (ld >= 0 && ld < L_) {
      int u = uid[b * L_ + ld];
      vv = ws_f[WS_KU + u * DIM_ + c];
    }
    sx[t] = vv;
  }
  __syncthreads();
  if (t < DIM_) {
    float acc = conv_b[t];
    for (int i = 0; i < DIM_; ++i) {
      acc += sx[0 * DIM_ + i] * s_cw[(i * 3 + 0) * CWP_ + t];
      acc += sx[1 * DIM_ + i] * s_cw[(i * 3 + 1) * CWP_ + t];
      acc += sx[2 * DIM_ + i] * s_cw[(i * 3 + 2) * CWP_ + t];
    }
    swr[t] = acc;
  }
  __syncthreads();
  if (t < KU_) {
    float acc = 0.f;
    for (int d = 0; d < DIM_; ++d) acc += swr[d] * s_ur[t * URP_ + d];
    slog[t] = acc;
  }
  __syncthreads();
  sred[t] = (t < KU_) ? slog[t] : -1e30f;
  __syncthreads();
  for (int off = 128; off > 0; off >>= 1) {
    if (t < off) sred[t] = fmaxf(sred[t], sred[t + off]);
    __syncthreads();
  }
  float m = sred[0];
  __syncthreads();
  sred[t] = (t < KU_) ? expf(slog[t] - m) : 0.f;
  __syncthreads();
  for (int off = 128; off > 0; off >>= 1) {
    if (t < off) sred[t] += sred[t + off];
    __syncthreads();
  }
  float ls = m + logf(sred[0]);
  if (t < KU_) {
    int u = uid[b * L_ + l];
    float lp = slog[t] - ls;
    ws_plp[bl * KU_ + t] = ws_f[WS_CLP + u * KU_ + t] + CTXW_ * lp;
  }
}

// -------------------------------------------------------------------------
// Kernel 3: DP. grid (B*L, 4), 256 threads, TWO vocab entries per thread.
__global__ __launch_bounds__(256, 4) void dp_kernel(
    const int* __restrict__ lengths,
    const int* __restrict__ vocab_ids,      // (V, MAXVL)
    const int* __restrict__ vocab_lengths,  // (V,)
    const float* __restrict__ ws_plp,       // (B*L, KU)
    unsigned long long* __restrict__ g_best)
{
  int bl = blockIdx.x;
  int b = bl / L_, l = bl % L_;
  int len_b = lengths[b];
  int imax = len_b - l;
  if (imax > MAX_WL_) imax = MAX_WL_;
  if (imax < MIN_WL_) return;  // uniform across block

  __shared__ float srows[MAX_WL_ * KU_];
  __shared__ unsigned long long swave[4];
  int t = threadIdx.x;
  // float4 staging: imax*100 dwords = imax*25 float4, 16B-aligned
  {
    const float4* src = (const float4*)(ws_plp + bl * KU_);
    float4* dst = (float4*)srows;
    int nf4 = imax * (KU_ / 4);
    for (int k = t; k < nf4; k += 256) dst[k] = src[k];
  }
  __syncthreads();

  int v0 = blockIdx.y * 512 + t;       // always < 2000
  int v1 = v0 + 256;
  bool has1 = (v1 < V_);
  unsigned long long bestKey = 0ull;

  int vid0[MAXVL_], vid1[MAXVL_];
#pragma unroll
  for (int j = 0; j < MAXVL_; ++j) vid0[j] = vocab_ids[v0 * MAXVL_ + j];
  if (has1) {
#pragma unroll
    for (int j = 0; j < MAXVL_; ++j) vid1[j] = vocab_ids[v1 * MAXVL_ + j];
  } else {
#pragma unroll
    for (int j = 0; j < MAXVL_; ++j) vid1[j] = 0;
  }
  int vlen0 = vocab_lengths[v0];
  int vlen1 = has1 ? vocab_lengths[v1] : MIN_WL_;
  float prev0[MAXVL_ + 1], prev1[MAXVL_ + 1];
#pragma unroll
  for (int j = 0; j <= MAXVL_; ++j) { prev0[j] = -IDC_ * (float)j; prev1[j] = prev0[j]; }

  for (int i = 1; i <= imax; ++i) {
    const float* row = &srows[(i - 1) * KU_];
    float s0[MAXVL_], s1[MAXVL_];
#pragma unroll
    for (int j = 0; j < MAXVL_; ++j) { s0[j] = row[vid0[j]]; s1[j] = row[vid1[j]]; }
    float rowstart = -IDC_ * (float)i;
    float d0 = prev0[0], rp0 = rowstart;
    float d1 = prev1[0], rp1 = rowstart;
    prev0[0] = rowstart; prev1[0] = rowstart;
#pragma unroll
    for (int j = 1; j <= MAXVL_; ++j) {
      float t0 = fmaxf(d0 + s0[j - 1], fmaxf(prev0[j], rp0) - IDC_);
      d0 = prev0[j]; prev0[j] = t0; rp0 = t0;
      float t1 = fmaxf(d1 + s1[j - 1], fmaxf(prev1[j], rp1) - IDC_);
      d1 = prev1[j]; prev1[j] = t1; rp1 = t1;
    }
    if (i >= MIN_WL_) {
      float unext = (float)(len_b - i) * LOG_UNEXT_;
      unsigned int idx_base = (unsigned int)(l * (NE_ * V_) + (i - MIN_WL_) * V_);
      float ll0 = prev0[MIN_WL_];
#pragma unroll
      for (int jj = MIN_WL_ + 1; jj <= MAXVL_; ++jj) if (vlen0 == jj) ll0 = prev0[jj];
      {
        float score = ll0 + unext;
        unsigned int idx = idx_base + (unsigned int)v0;
        unsigned int u = __float_as_uint(score);
        u = (u & 0x80000000u) ? ~u : (u | 0x80000000u);
        unsigned long long key = ((unsigned long long)u << 32) | (unsigned long long)(~idx);
        if (key > bestKey) bestKey = key;
      }
      if (has1) {
        float ll1 = prev1[MIN_WL_];
#pragma unroll
        for (int jj = MIN_WL_ + 1; jj <= MAXVL_; ++jj) if (vlen1 == jj) ll1 = prev1[jj];
        float score = ll1 + unext;
        unsigned int idx = idx_base + (unsigned int)v1;
        unsigned int u = __float_as_uint(score);
        u = (u & 0x80000000u) ? ~u : (u | 0x80000000u);
        unsigned long long key = ((unsigned long long)u << 32) | (unsigned long long)(~idx);
        if (key > bestKey) bestKey = key;
      }
    }
  }

#pragma unroll
  for (int off = 32; off > 0; off >>= 1) {
    unsigned long long o = __shfl_down(bestKey, off);
    if (o > bestKey) bestKey = o;
  }
  int wid = t >> 6;
  if ((t & 63) == 0) swave[wid] = bestKey;
  __syncthreads();
  if (t == 0) {
    unsigned long long k0 = swave[0];
    for (int w = 1; w < 4; ++w)
      if (swave[w] > k0) k0 = swave[w];
    atomicMax(g_best + (size_t)b * BEST_STRIDE, k0);
  }
}

// -------------------------------------------------------------------------
__global__ void decode_kernel(const unsigned long long* __restrict__ g_best,
                              float* __restrict__ out)
{
  int t = threadIdx.x;
  if (t < B_) {
    unsigned long long key = g_best[t * BEST_STRIDE];
    unsigned int u = (unsigned int)(key >> 32);
    unsigned int idx = ~((unsigned int)(key & 0xFFFFFFFFull));
    unsigned int bits = (u & 0x80000000u) ? (u & 0x7FFFFFFFu) : ~u;
    float val = __uint_as_float(bits);
    int start = (int)(idx / (NE_ * V_));
    int rem = (int)(idx % (NE_ * V_));
    int e = rem / V_;
    int vv = rem % V_;
    out[t] = (float)start;
    out[B_ + t] = (float)(start + MIN_WL_ + e - 1);
    out[2 * B_ + t] = val;
    out[3 * B_ + t] = (float)vv;
  }
}

// -------------------------------------------------------------------------
extern "C" void kernel_launch(void* const* d_in, const int* in_sizes, int n_in,
                              void* d_out, int out_size, void* d_ws, size_t ws_size,
                              hipStream_t stream)
{
  const int* uid            = (const int*)d_in[0];
  const int* lengths        = (const int*)d_in[1];
  const float* unit_repr    = (const float*)d_in[2];
  const float* aligner_w    = (const float*)d_in[3];
  const float* conv_w       = (const float*)d_in[4];
  const float* conv_b       = (const float*)d_in[5];
  const int* vocab_ids      = (const int*)d_in[6];
  const int* vocab_lengths  = (const int*)d_in[7];
  float* out = (float*)d_out;
  float* ws_f = (float*)d_ws;
  unsigned long long* g_best =
      (unsigned long long*)((char*)d_ws + WS_BEST_BYTES);

  prep_kernel<<<LU_, 128, 0, stream>>>(unit_repr, aligner_w, ws_f, g_best,
                                       out + 4 * B_);
  ctx_kernel<<<B_ * L_, 256, 0, stream>>>(uid, unit_repr, conv_w, conv_b, ws_f,
                                          ws_f + WS_PLP);
  dim3 g3(B_ * L_, 4);
  dp_kernel<<<g3, 256, 0, stream>>>(lengths, vocab_ids, vocab_lengths,
                                    ws_f + WS_PLP, g_best);
  decode_kernel<<<1, 64, 0, stream>>>(g_best, out);
}